// Round 8
// baseline (354.242 us; speedup 1.0000x reference)
//
#include <hip/hip_runtime.h>
#include <hip/hip_bf16.h>

constexpr int HID = 256;
constexpr int CAP = 64;          // fixed CSR capacity per node (max deg ~45)
constexpr float NEG = 0.2f;
constexpr float EPS = 1e-5f;

typedef __attribute__((ext_vector_type(8))) short bf16x8;
typedef __attribute__((ext_vector_type(4))) float f32x4;

static __device__ __forceinline__ unsigned short f2bf(float f) {
    unsigned u = __builtin_bit_cast(unsigned, f);
    u += 0x7fffu + ((u >> 16) & 1u);
    return (unsigned short)(u >> 16);
}
static __device__ __forceinline__ float bf2f(unsigned short h) {
    return __builtin_bit_cast(float, ((unsigned)h) << 16);
}
static __device__ __forceinline__ float elk(float v) {
    v = v > 0.f ? v : NEG * v;
    return __expf(v);
}

// ---------------- fused preprocessing ----------------
// NOTE: lo/hi written ONLY by the bounds task (each graph id exactly once);
// zero-initializing them here would race (round-4 bug). csr is -1-initialized
// here; k_fill (stream-ordered later) overwrites real slots.

__device__ __forceinline__ void frag_task(const float* __restrict__ W,
                                          ushort* __restrict__ out,
                                          int KS, int nmat, int q) {
    int per = KS * 1024;
    if (q >= per * nmat) return;
    int mat = q / per, r = q - mat * per;
    int l = r & 63, nf = (r >> 6) & 15, kk = r >> 10;
    const float* Wm = W + (size_t)mat * KS * 32 * 256;
    int kb = kk * 32 + ((l >> 4) << 3);
    int col = nf * 16 + (l & 15);
    bf16x8 v;
#pragma unroll
    for (int j = 0; j < 8; ++j) v[j] = (short)f2bf(Wm[(size_t)(kb + j) * 256 + col]);
    *(bf16x8*)(out + (size_t)q * 8) = v;
}

__global__ void k_pre(const float* __restrict__ x, ushort* __restrict__ xb,
                      const float* __restrict__ cls, ushort* __restrict__ h0,
                      const float* __restrict__ W_in, ushort* __restrict__ wf_in,
                      const float* __restrict__ W_gat, ushort* __restrict__ wf_gat,
                      const int* __restrict__ batch, int* lo, int* hi,
                      int* cursor, int* csr, int N, int B, int n_new) {
    int bid = blockIdx.x, t = threadIdx.x;
    const int nb_cvt  = (N * 128 / 4 + 255) / 256;
    const int nb_init = (n_new + 255) / 256;
    const int nb_csr  = (n_new * CAP + 255) / 256;
    const int nb_bnd  = (N + 255) / 256;
    const int nb_cls  = (B * HID / 4 + 255) / 256;
    const int nb_fin  = (4 * 1024 + 255) / 256;

    if (bid < nb_cvt) {
        int i = bid * 256 + t;
        int n4 = N * 128 / 4;
        if (i < n4) {
            float4 v = ((const float4*)x)[i];
            ushort4 o;
            o.x = f2bf(v.x); o.y = f2bf(v.y); o.z = f2bf(v.z); o.w = f2bf(v.w);
            ((ushort4*)xb)[i] = o;
        }
        return;
    }
    bid -= nb_cvt;
    if (bid < nb_init) {
        int i = bid * 256 + t;
        if (i < n_new) cursor[i] = 0;
        return;
    }
    bid -= nb_init;
    if (bid < nb_csr) {
        int i = bid * 256 + t;
        if (i < n_new * CAP) csr[i] = -1;
        return;
    }
    bid -= nb_csr;
    if (bid < nb_bnd) {
        int i = bid * 256 + t;
        if (i < N) {
            int b = batch[i];
            if (i == 0 || batch[i - 1] != b) lo[b] = i;
            if (i == N - 1 || batch[i + 1] != b) hi[b] = i + 1;
        }
        return;
    }
    bid -= nb_bnd;
    if (bid < nb_cls) {
        int i = bid * 256 + t;
        if (i < B * HID / 4) {
            int ch = (i & 63) * 4;
            ushort4 o;
            o.x = f2bf(cls[ch]); o.y = f2bf(cls[ch + 1]);
            o.z = f2bf(cls[ch + 2]); o.w = f2bf(cls[ch + 3]);
            ((ushort4*)h0)[i] = o;
        }
        return;
    }
    bid -= nb_cls;
    if (bid < nb_fin) {
        frag_task(W_in, wf_in, 4, 1, bid * 256 + t);
        return;
    }
    bid -= nb_fin;
    frag_task(W_gat, wf_gat, 8, 3, bid * 256 + t);
}

// ---------------- direct CSR fill (fixed capacity, no scan) ----------------

__global__ void k_fill(const int* __restrict__ src0, const int* __restrict__ dst0,
                       int* cursor, int* __restrict__ csr, int E, int B) {
    int e = blockIdx.x * blockDim.x + threadIdx.x;
    if (e < E) {
        int d = dst0[e] + B;
        int p = atomicAdd(&cursor[d], 1);
        if (p < CAP) csr[d * CAP + p] = src0[e] + B;
    }
}

// ---------------- MFMA GEMM: out[row][0:256] = A[row][0:K] @ W ----------------

template <int KS, bool ATT, bool BIAS>
__global__ __launch_bounds__(128, 1) void k_mgemm(
    const ushort* __restrict__ A, const ushort* __restrict__ Wf,
    const float* __restrict__ bias, ushort* __restrict__ outb,
    const float* __restrict__ att_s, const float* __restrict__ att_d,
    float* __restrict__ al_s, float* __restrict__ al_d, int rows)
{
    constexpr int K = KS * 32;
    int lane = threadIdx.x & 63, w = threadIdx.x >> 6;
    int rbase = blockIdx.x * 64 + w * 32;
    int arow0 = rbase + (lane & 15);
    int kofs = (lane >> 4) << 3;

    f32x4 acc[2][16];
#pragma unroll
    for (int mf = 0; mf < 2; ++mf)
#pragma unroll
        for (int nf = 0; nf < 16; ++nf) acc[mf][nf] = (f32x4){0.f, 0.f, 0.f, 0.f};

    const ushort* a0p = A + (size_t)arow0 * K + kofs;
    const ushort* a1p = a0p + (size_t)16 * K;
    bool g0 = arow0 < rows, g1 = (arow0 + 16) < rows;

#pragma unroll
    for (int kk = 0; kk < KS; ++kk) {
        bf16x8 af0 = {0, 0, 0, 0, 0, 0, 0, 0}, af1 = {0, 0, 0, 0, 0, 0, 0, 0};
        if (g0) af0 = *(const bf16x8*)(a0p + kk * 32);
        if (g1) af1 = *(const bf16x8*)(a1p + kk * 32);
        const bf16x8* wp = ((const bf16x8*)Wf) + (size_t)(kk * 16) * 64 + lane;
#pragma unroll
        for (int nf = 0; nf < 16; ++nf) {
            bf16x8 bv = wp[nf * 64];
            acc[0][nf] = __builtin_amdgcn_mfma_f32_16x16x32_bf16(af0, bv, acc[0][nf], 0, 0, 0);
            acc[1][nf] = __builtin_amdgcn_mfma_f32_16x16x32_bf16(af1, bv, acc[1][nf], 0, 0, 0);
        }
    }

    int rg = (lane >> 4) * 4;
    int c0 = lane & 15;
    float bv[16];
    if (BIAS) {
#pragma unroll
        for (int nf = 0; nf < 16; ++nf) bv[nf] = bias[nf * 16 + c0];
    }
#pragma unroll
    for (int mf = 0; mf < 2; ++mf)
#pragma unroll
        for (int r = 0; r < 4; ++r) {
            int row = rbase + mf * 16 + rg + r;
            if (row < rows) {
#pragma unroll
                for (int nf = 0; nf < 16; ++nf) {
                    float v = acc[mf][nf][r];
                    if (BIAS) v += bv[nf];
                    outb[(size_t)row * HID + nf * 16 + c0] = f2bf(v);
                }
            }
        }

    if (ATT) {
        float as[16], ad[16];
#pragma unroll
        for (int nf = 0; nf < 16; ++nf) {
            as[nf] = att_s[nf * 16 + c0];
            ad[nf] = att_d[nf * 16 + c0];
        }
#pragma unroll
        for (int mf = 0; mf < 2; ++mf)
#pragma unroll
            for (int r = 0; r < 4; ++r) {
                float ps[4] = {0.f, 0.f, 0.f, 0.f}, pd[4] = {0.f, 0.f, 0.f, 0.f};
#pragma unroll
                for (int nf = 0; nf < 16; ++nf) {
                    float v = acc[mf][nf][r];
                    ps[nf >> 2] += v * as[nf];
                    pd[nf >> 2] += v * ad[nf];
                }
#pragma unroll
                for (int o = 1; o < 16; o <<= 1) {
#pragma unroll
                    for (int h = 0; h < 4; ++h) {
                        ps[h] += __shfl_xor(ps[h], o, 64);
                        pd[h] += __shfl_xor(pd[h], o, 64);
                    }
                }
                int row = rbase + mf * 16 + rg + r;
                if (c0 == 0 && row < rows) {
                    float4 vs, vd;
                    vs.x = ps[0]; vs.y = ps[1]; vs.z = ps[2]; vs.w = ps[3];
                    vd.x = pd[0]; vd.y = pd[1]; vd.z = pd[2]; vd.w = pd[3];
                    *(float4*)(al_s + row * 4) = vs;
                    *(float4*)(al_d + row * 4) = vd;
                }
            }
    }
}

// ---------------- GAT aggregation + bias + residual + LayerNorm ----------------
// Fixed-stride CSR (CAP=64/node), branch-free batched gather with INLINE alpha:
// per int4 batch of 4 edges: 4 als dword gathers (L2-hot 321KB) + 4 exp +
// 4 independent 512B xs row gathers. Pad slots: csr=-1 -> mask alpha to 0,
// clamp src to 0 (row 0 stays hot). One wave per node.
// lane = es(2 slots) x cg(32 groups of 8 ch); head = cg>>3.

__global__ __launch_bounds__(256, 4) void k_agg(
    const ushort* __restrict__ hb, const ushort* __restrict__ xs,
    const float* __restrict__ als, const float* __restrict__ ald,
    const int* __restrict__ cursor, const int* __restrict__ csr,
    const int* __restrict__ batch, const int* __restrict__ lo,
    const int* __restrict__ hi,
    const float* __restrict__ b_gat, const float* __restrict__ ln_g,
    const float* __restrict__ ln_b,
    ushort* __restrict__ h_out, int n_new, int B)
{
    int t = threadIdx.x, w = t >> 6, lane = t & 63;
    int n = blockIdx.x * 4 + w;
    if (n >= n_new) return;
    int es = lane >> 5, cg = lane & 31, head = cg >> 3;

    float ald_h = ald[n * 4 + head];
    float acc[8] = {0.f, 0.f, 0.f, 0.f, 0.f, 0.f, 0.f, 0.f};
    float den = 0.f;

    if (n >= B) {
        int gdeg = cursor[n];
        gdeg = gdeg < CAP ? gdeg : CAP;
        int gdegp = (gdeg + 7) & ~7;
        int clssrc = batch[n - B];
        bf16x8 xcls  = *((const bf16x8*)(xs + (size_t)clssrc * HID) + cg);
        bf16x8 xself = *((const bf16x8*)(xs + (size_t)n * HID) + cg);
        float acl = elk(als[clssrc * 4 + head] + ald_h);
        float asf = elk(als[n * 4 + head] + ald_h);

        const int4* cp = (const int4*)(csr + n * CAP);
#pragma unroll 2
        for (int eb = 0; eb < gdegp; eb += 8) {
            int idx = (eb >> 2) + es;
            int4 s4 = cp[idx];
            int s0 = s4.x < 0 ? 0 : s4.x;
            int s1 = s4.y < 0 ? 0 : s4.y;
            int s2 = s4.z < 0 ? 0 : s4.z;
            int s3 = s4.w < 0 ? 0 : s4.w;
            bf16x8 x0 = *((const bf16x8*)(xs + (size_t)s0 * HID) + cg);
            bf16x8 x1 = *((const bf16x8*)(xs + (size_t)s1 * HID) + cg);
            bf16x8 x2 = *((const bf16x8*)(xs + (size_t)s2 * HID) + cg);
            bf16x8 x3 = *((const bf16x8*)(xs + (size_t)s3 * HID) + cg);
            float a0 = s4.x < 0 ? 0.f : elk(als[s0 * 4 + head] + ald_h);
            float a1 = s4.y < 0 ? 0.f : elk(als[s1 * 4 + head] + ald_h);
            float a2 = s4.z < 0 ? 0.f : elk(als[s2 * 4 + head] + ald_h);
            float a3 = s4.w < 0 ? 0.f : elk(als[s3 * 4 + head] + ald_h);
            den += a0 + a1 + a2 + a3;
#pragma unroll
            for (int j = 0; j < 8; ++j) {
                acc[j] += a0 * bf2f((unsigned short)x0[j]);
                acc[j] += a1 * bf2f((unsigned short)x1[j]);
                acc[j] += a2 * bf2f((unsigned short)x2[j]);
                acc[j] += a3 * bf2f((unsigned short)x3[j]);
            }
        }
        if (es == 0) {
            den += acl + asf;
#pragma unroll
            for (int j = 0; j < 8; ++j)
                acc[j] += acl * bf2f((unsigned short)xcls[j]) +
                          asf * bf2f((unsigned short)xself[j]);
        }
    } else {
        // CLS node: contiguous source range [B+lo, B+hi).
        int cb = B + lo[n], cdeg = hi[n] - lo[n];
        bf16x8 xself = *((const bf16x8*)(xs + (size_t)n * HID) + cg);
        float asf = elk(als[n * 4 + head] + ald_h);
        for (int eb = 0; eb < cdeg; eb += 8) {
            int b0 = eb + es * 4;
#pragma unroll
            for (int k = 0; k < 4; ++k) {
                int e = b0 + k;
                int ec = e < cdeg ? e : cdeg - 1;
                int src = cb + ec;
                float a = e < cdeg ? elk(als[src * 4 + head] + ald_h) : 0.f;
                bf16x8 xv = *((const bf16x8*)(xs + (size_t)src * HID) + cg);
                den += a;
#pragma unroll
                for (int j = 0; j < 8; ++j) acc[j] += a * bf2f((unsigned short)xv[j]);
            }
        }
        if (es == 0) {
            den += asf;
#pragma unroll
            for (int j = 0; j < 8; ++j) acc[j] += asf * bf2f((unsigned short)xself[j]);
        }
    }

    // reduce across the two edge slots (xor bit 5)
#pragma unroll
    for (int j = 0; j < 8; ++j) acc[j] += __shfl_xor(acc[j], 32, 64);
    den += __shfl_xor(den, 32, 64);
    float inv = 1.f / (den + 1e-16f);

    // residual + bias
    bf16x8 hv = *((const bf16x8*)(hb + (size_t)n * HID) + cg);
    const float4* bgp = (const float4*)(b_gat + cg * 8);
    float4 bg0 = bgp[0], bg1 = bgp[1];
    float bg[8] = {bg0.x, bg0.y, bg0.z, bg0.w, bg1.x, bg1.y, bg1.z, bg1.w};
    float r[8];
#pragma unroll
    for (int j = 0; j < 8; ++j)
        r[j] = bf2f((unsigned short)hv[j]) + acc[j] * inv + bg[j];

    // LayerNorm: butterfly over the 32 channel groups (bits 0..4)
    float ss = 0.f;
#pragma unroll
    for (int j = 0; j < 8; ++j) ss += r[j];
#pragma unroll
    for (int o = 1; o < 32; o <<= 1) ss += __shfl_xor(ss, o, 64);
    float mu = ss * (1.f / HID);
    float vv = 0.f;
#pragma unroll
    for (int j = 0; j < 8; ++j) { r[j] -= mu; vv += r[j] * r[j]; }
#pragma unroll
    for (int o = 1; o < 32; o <<= 1) vv += __shfl_xor(vv, o, 64);
    float rs = rsqrtf(vv * (1.f / HID) + EPS);

    if (es == 0) {
        const float4* gp = (const float4*)(ln_g + cg * 8);
        const float4* bp = (const float4*)(ln_b + cg * 8);
        float4 g0 = gp[0], g1 = gp[1];
        float4 lb0 = bp[0], lb1 = bp[1];
        float gg[8] = {g0.x, g0.y, g0.z, g0.w, g1.x, g1.y, g1.z, g1.w};
        float bb[8] = {lb0.x, lb0.y, lb0.z, lb0.w, lb1.x, lb1.y, lb1.z, lb1.w};
        bf16x8 o8;
#pragma unroll
        for (int j = 0; j < 8; ++j) o8[j] = (short)f2bf(r[j] * rs * gg[j] + bb[j]);
        *((bf16x8*)(h_out + (size_t)n * HID) + cg) = o8;
    }
}

// ---------------- output projection (B x 256 @ 256 x 256) ----------------

__global__ __launch_bounds__(256) void k_out(
    const ushort* __restrict__ h, const float* __restrict__ Wm,
    const float* __restrict__ bias, float* __restrict__ z)
{
    __shared__ float hs[HID];
    int b = blockIdx.x, t = threadIdx.x;
    hs[t] = bf2f(h[(size_t)b * HID + t]);
    __syncthreads();
    float acc = bias[t];
#pragma unroll 8
    for (int k = 0; k < HID; ++k) acc += hs[k] * Wm[k * HID + t];
    z[(size_t)b * HID + t] = acc;
}

// ---------------- launch ----------------

extern "C" void kernel_launch(void* const* d_in, const int* in_sizes, int n_in,
                              void* d_out, int out_size, void* d_ws, size_t ws_size,
                              hipStream_t stream) {
    const float* x      = (const float*)d_in[0];
    const int*   ei     = (const int*)d_in[1];
    const int*   batch  = (const int*)d_in[2];
    const float* W_in   = (const float*)d_in[3];
    const float* b_in   = (const float*)d_in[4];
    const float* cls    = (const float*)d_in[5];
    const float* W_gat  = (const float*)d_in[6];
    const float* att_s  = (const float*)d_in[7];
    const float* att_d  = (const float*)d_in[8];
    const float* b_gat  = (const float*)d_in[9];
    const float* ln_g   = (const float*)d_in[10];
    const float* ln_b   = (const float*)d_in[11];
    const float* W_out  = (const float*)d_in[12];
    const float* b_out  = (const float*)d_in[13];

    const int N = in_sizes[0] / 128;
    const int E = in_sizes[1] / 2;
    const int B = 64;
    const int n_new = N + B;
    const int* src0 = ei;
    const int* dst0 = ei + E;

    char* p = (char*)d_ws;
    auto alloc = [&](size_t bytes) -> void* {
        void* r = (void*)p;
        p += (bytes + 255) & ~(size_t)255;
        return r;
    };
    int*    cursor = (int*)alloc((size_t)n_new * 4);
    int*    csr    = (int*)alloc((size_t)n_new * CAP * 4);
    int*    lo     = (int*)alloc((size_t)B * 4);
    int*    hi     = (int*)alloc((size_t)B * 4);
    ushort* xb     = (ushort*)alloc((size_t)N * 128 * 2);
    ushort* h0b    = (ushort*)alloc((size_t)n_new * HID * 2);
    ushort* h1b    = (ushort*)alloc((size_t)n_new * HID * 2);
    ushort* xsb    = (ushort*)alloc((size_t)n_new * HID * 2);
    float*  als    = (float*)alloc((size_t)n_new * 4 * 4);
    float*  aldv   = (float*)alloc((size_t)n_new * 4 * 4);
    ushort* wf_in  = (ushort*)alloc((size_t)4 * 1024 * 8 * 2);
    ushort* wf_gat = (ushort*)alloc((size_t)3 * 8 * 1024 * 8 * 2);

    const int nb_pre = (N * 128 / 4 + 255) / 256 + (n_new + 255) / 256 +
                       (n_new * CAP + 255) / 256 + (N + 255) / 256 +
                       (B * HID / 4 + 255) / 256 +
                       (4 * 1024 + 255) / 256 + (3 * 8 * 1024 + 255) / 256;
    k_pre<<<nb_pre, 256, 0, stream>>>(x, xb, cls, h0b, W_in, wf_in, W_gat, wf_gat,
                                      batch, lo, hi, cursor, csr, N, B, n_new);
    k_fill<<<(E + 255) / 256, 256, 0, stream>>>(src0, dst0, cursor, csr, E, B);

    k_mgemm<4, false, true><<<(N + 63) / 64, 128, 0, stream>>>(
        xb, wf_in, b_in, h0b + (size_t)B * HID, nullptr, nullptr, nullptr, nullptr, N);

    ushort* cur = h0b;
    ushort* nxt = h1b;
    for (int l = 0; l < 3; ++l) {
        k_mgemm<8, true, false><<<(n_new + 63) / 64, 128, 0, stream>>>(
            cur, wf_gat + (size_t)l * 65536, nullptr, xsb,
            att_s + l * HID, att_d + l * HID, als, aldv, n_new);
        k_agg<<<(n_new + 3) / 4, 256, 0, stream>>>(
            cur, xsb, als, aldv, cursor, csr, batch, lo, hi,
            b_gat + l * HID, ln_g + l * HID, ln_b + l * HID, nxt, n_new, B);
        ushort* tmp = cur; cur = nxt; nxt = tmp;
    }
    k_out<<<B, 256, 0, stream>>>(cur, W_out, b_out, (float*)d_out);
}

// Round 9
// 248.759 us; speedup vs baseline: 1.4240x; 1.4240x over previous
//
#include <hip/hip_runtime.h>
#include <hip/hip_bf16.h>

constexpr int HID = 256;
constexpr int CAP = 64;          // fixed CSR capacity/node (mean deg 16, P(>64)~1e-19)
constexpr float NEG = 0.2f;
constexpr float EPS = 1e-5f;

typedef __attribute__((ext_vector_type(8))) short bf16x8;
typedef __attribute__((ext_vector_type(4))) float f32x4;

static __device__ __forceinline__ unsigned short f2bf(float f) {
    unsigned u = __builtin_bit_cast(unsigned, f);
    u += 0x7fffu + ((u >> 16) & 1u);
    return (unsigned short)(u >> 16);
}
static __device__ __forceinline__ float bf2f(unsigned short h) {
    return __builtin_bit_cast(float, ((unsigned)h) << 16);
}
static __device__ __forceinline__ float elk(float v) {
    v = v > 0.f ? v : NEG * v;
    return __expf(v);
}

// ---------------- fused preprocessing ----------------
// NOTE: lo/hi written ONLY by the bounds task (each graph id exactly once);
// zero-initializing them here would race (round-4 bug). csr is -1-initialized
// here; k_fill (stream-ordered later) overwrites real slots.

__device__ __forceinline__ void frag_task(const float* __restrict__ W,
                                          ushort* __restrict__ out,
                                          int KS, int nmat, int q) {
    int per = KS * 1024;
    if (q >= per * nmat) return;
    int mat = q / per, r = q - mat * per;
    int l = r & 63, nf = (r >> 6) & 15, kk = r >> 10;
    const float* Wm = W + (size_t)mat * KS * 32 * 256;
    int kb = kk * 32 + ((l >> 4) << 3);
    int col = nf * 16 + (l & 15);
    bf16x8 v;
#pragma unroll
    for (int j = 0; j < 8; ++j) v[j] = (short)f2bf(Wm[(size_t)(kb + j) * 256 + col]);
    *(bf16x8*)(out + (size_t)q * 8) = v;
}

__global__ void k_pre(const float* __restrict__ x, ushort* __restrict__ xb,
                      const float* __restrict__ cls, ushort* __restrict__ h0,
                      const float* __restrict__ W_in, ushort* __restrict__ wf_in,
                      const float* __restrict__ W_gat, ushort* __restrict__ wf_gat,
                      const int* __restrict__ batch, int* lo, int* hi,
                      int* cursor, int* csr, int N, int B, int n_new) {
    int bid = blockIdx.x, t = threadIdx.x;
    const int nb_cvt  = (N * 128 / 4 + 255) / 256;
    const int nb_init = (n_new + 255) / 256;
    const int nb_csr  = (n_new * CAP + 255) / 256;
    const int nb_bnd  = (N + 255) / 256;
    const int nb_cls  = (B * HID / 4 + 255) / 256;
    const int nb_fin  = (4 * 1024 + 255) / 256;

    if (bid < nb_cvt) {
        int i = bid * 256 + t;
        int n4 = N * 128 / 4;
        if (i < n4) {
            float4 v = ((const float4*)x)[i];
            ushort4 o;
            o.x = f2bf(v.x); o.y = f2bf(v.y); o.z = f2bf(v.z); o.w = f2bf(v.w);
            ((ushort4*)xb)[i] = o;
        }
        return;
    }
    bid -= nb_cvt;
    if (bid < nb_init) {
        int i = bid * 256 + t;
        if (i < n_new) cursor[i] = 0;
        return;
    }
    bid -= nb_init;
    if (bid < nb_csr) {
        int i = bid * 256 + t;
        if (i < n_new * CAP) csr[i] = -1;
        return;
    }
    bid -= nb_csr;
    if (bid < nb_bnd) {
        int i = bid * 256 + t;
        if (i < N) {
            int b = batch[i];
            if (i == 0 || batch[i - 1] != b) lo[b] = i;
            if (i == N - 1 || batch[i + 1] != b) hi[b] = i + 1;
        }
        return;
    }
    bid -= nb_bnd;
    if (bid < nb_cls) {
        int i = bid * 256 + t;
        if (i < B * HID / 4) {
            int ch = (i & 63) * 4;
            ushort4 o;
            o.x = f2bf(cls[ch]); o.y = f2bf(cls[ch + 1]);
            o.z = f2bf(cls[ch + 2]); o.w = f2bf(cls[ch + 3]);
            ((ushort4*)h0)[i] = o;
        }
        return;
    }
    bid -= nb_cls;
    if (bid < nb_fin) {
        frag_task(W_in, wf_in, 4, 1, bid * 256 + t);
        return;
    }
    bid -= nb_fin;
    frag_task(W_gat, wf_gat, 8, 3, bid * 256 + t);
}

// ---------------- direct CSR fill (fixed capacity, no count/scan) ----------------

__global__ void k_fill(const int* __restrict__ src0, const int* __restrict__ dst0,
                       int* cursor, int* __restrict__ csr, int E, int B) {
    int e = blockIdx.x * blockDim.x + threadIdx.x;
    if (e < E) {
        int d = dst0[e] + B;
        int p = atomicAdd(&cursor[d], 1);
        if (p < CAP) csr[d * CAP + p] = src0[e] + B;
    }
}

// ---------------- per-edge attention weights (per layer) ----------------
// Fixed-stride slots: q = d*CAP + p, so dst = q>>6 (no csrd array).
// a4T[h*(n_new*CAP) + q] : weight of slot q for head h (0 for pad slots).
// Writes gated on p < padded-degree (k_agg never reads beyond it).
// aself[n*4+h]: self-loop; acls[n*4+h]: CLS->node (n>=B);
// aclsinT[h*n_new+n]: node n -> its CLS weight (planar).

__global__ void k_alpha(const int* __restrict__ csr, const int* __restrict__ cursor,
                        const float* __restrict__ als, const float* __restrict__ ald,
                        const int* __restrict__ batch,
                        float* __restrict__ a4T, float* __restrict__ acls,
                        float* __restrict__ aself, float* __restrict__ aclsinT,
                        int n_new, int B) {
    const int NSLOT = n_new * CAP;
    int i = blockIdx.x * 256 + threadIdx.x;
    if (i < NSLOT) {
        int d = i >> 6, p = i & (CAP - 1);
        int deg = cursor[d];
        deg = deg < CAP ? deg : CAP;
        int degp = (deg + 7) & ~7;
        if (p >= degp) return;
        int s = csr[i];
        float ox = 0.f, oy = 0.f, oz = 0.f, ow = 0.f;
        if (s >= 0) {
            float4 s4 = ((const float4*)als)[s];
            float4 d4 = ((const float4*)ald)[d];
            ox = elk(s4.x + d4.x);
            oy = elk(s4.y + d4.y);
            oz = elk(s4.z + d4.z);
            ow = elk(s4.w + d4.w);
        }
        a4T[i] = ox;
        a4T[(size_t)NSLOT + i] = oy;
        a4T[(size_t)2 * NSLOT + i] = oz;
        a4T[(size_t)3 * NSLOT + i] = ow;
        return;
    }
    int n = i - NSLOT;
    if (n < n_new) {
        float4 d4 = ((const float4*)ald)[n];
        float4 s4 = ((const float4*)als)[n];
        float4 o;
        o.x = elk(s4.x + d4.x);
        o.y = elk(s4.y + d4.y);
        o.z = elk(s4.z + d4.z);
        o.w = elk(s4.w + d4.w);
        ((float4*)aself)[n] = o;
        if (n >= B) {
            int c = batch[n - B];
            float4 cs = ((const float4*)als)[c];
            float4 p4;
            p4.x = elk(cs.x + d4.x);
            p4.y = elk(cs.y + d4.y);
            p4.z = elk(cs.z + d4.z);
            p4.w = elk(cs.w + d4.w);
            ((float4*)acls)[n] = p4;
            float4 cd = ((const float4*)ald)[c];
            aclsinT[n] = elk(s4.x + cd.x);
            aclsinT[(size_t)n_new + n] = elk(s4.y + cd.y);
            aclsinT[(size_t)2 * n_new + n] = elk(s4.z + cd.z);
            aclsinT[(size_t)3 * n_new + n] = elk(s4.w + cd.w);
        }
    }
}

// ---------------- MFMA GEMM: out[row][0:256] = A[row][0:K] @ W ----------------

template <int KS, bool ATT, bool BIAS>
__global__ __launch_bounds__(128, 1) void k_mgemm(
    const ushort* __restrict__ A, const ushort* __restrict__ Wf,
    const float* __restrict__ bias, ushort* __restrict__ outb,
    const float* __restrict__ att_s, const float* __restrict__ att_d,
    float* __restrict__ al_s, float* __restrict__ al_d, int rows)
{
    constexpr int K = KS * 32;
    int lane = threadIdx.x & 63, w = threadIdx.x >> 6;
    int rbase = blockIdx.x * 64 + w * 32;
    int arow0 = rbase + (lane & 15);
    int kofs = (lane >> 4) << 3;

    f32x4 acc[2][16];
#pragma unroll
    for (int mf = 0; mf < 2; ++mf)
#pragma unroll
        for (int nf = 0; nf < 16; ++nf) acc[mf][nf] = (f32x4){0.f, 0.f, 0.f, 0.f};

    const ushort* a0p = A + (size_t)arow0 * K + kofs;
    const ushort* a1p = a0p + (size_t)16 * K;
    bool g0 = arow0 < rows, g1 = (arow0 + 16) < rows;

#pragma unroll
    for (int kk = 0; kk < KS; ++kk) {
        bf16x8 af0 = {0, 0, 0, 0, 0, 0, 0, 0}, af1 = {0, 0, 0, 0, 0, 0, 0, 0};
        if (g0) af0 = *(const bf16x8*)(a0p + kk * 32);
        if (g1) af1 = *(const bf16x8*)(a1p + kk * 32);
        const bf16x8* wp = ((const bf16x8*)Wf) + (size_t)(kk * 16) * 64 + lane;
#pragma unroll
        for (int nf = 0; nf < 16; ++nf) {
            bf16x8 bv = wp[nf * 64];
            acc[0][nf] = __builtin_amdgcn_mfma_f32_16x16x32_bf16(af0, bv, acc[0][nf], 0, 0, 0);
            acc[1][nf] = __builtin_amdgcn_mfma_f32_16x16x32_bf16(af1, bv, acc[1][nf], 0, 0, 0);
        }
    }

    int rg = (lane >> 4) * 4;
    int c0 = lane & 15;
    float bv[16];
    if (BIAS) {
#pragma unroll
        for (int nf = 0; nf < 16; ++nf) bv[nf] = bias[nf * 16 + c0];
    }
#pragma unroll
    for (int mf = 0; mf < 2; ++mf)
#pragma unroll
        for (int r = 0; r < 4; ++r) {
            int row = rbase + mf * 16 + rg + r;
            if (row < rows) {
#pragma unroll
                for (int nf = 0; nf < 16; ++nf) {
                    float v = acc[mf][nf][r];
                    if (BIAS) v += bv[nf];
                    outb[(size_t)row * HID + nf * 16 + c0] = f2bf(v);
                }
            }
        }

    if (ATT) {
        float as[16], ad[16];
#pragma unroll
        for (int nf = 0; nf < 16; ++nf) {
            as[nf] = att_s[nf * 16 + c0];
            ad[nf] = att_d[nf * 16 + c0];
        }
#pragma unroll
        for (int mf = 0; mf < 2; ++mf)
#pragma unroll
            for (int r = 0; r < 4; ++r) {
                float ps[4] = {0.f, 0.f, 0.f, 0.f}, pd[4] = {0.f, 0.f, 0.f, 0.f};
#pragma unroll
                for (int nf = 0; nf < 16; ++nf) {
                    float v = acc[mf][nf][r];
                    ps[nf >> 2] += v * as[nf];
                    pd[nf >> 2] += v * ad[nf];
                }
#pragma unroll
                for (int o = 1; o < 16; o <<= 1) {
#pragma unroll
                    for (int h = 0; h < 4; ++h) {
                        ps[h] += __shfl_xor(ps[h], o, 64);
                        pd[h] += __shfl_xor(pd[h], o, 64);
                    }
                }
                int row = rbase + mf * 16 + rg + r;
                if (c0 == 0 && row < rows) {
                    float4 vs, vd;
                    vs.x = ps[0]; vs.y = ps[1]; vs.z = ps[2]; vs.w = ps[3];
                    vd.x = pd[0]; vd.y = pd[1]; vd.z = pd[2]; vd.w = pd[3];
                    *(float4*)(al_s + row * 4) = vs;
                    *(float4*)(al_d + row * 4) = vd;
                }
            }
    }
}

// ---------------- GAT aggregation + bias + residual + LayerNorm ----------------
// Round-7 structure (the fast one): branch-free batched gather, alpha
// PRECOMPUTED planar (no dependent loads in the hot loop). Fixed-stride CSR.
// Per wave-iteration: 2 slots x {int4 srcs + float4 alphas + 4 independent
// 512B row gathers}; unroll 2 -> 16 rows in flight. One wave per node.
// lane = es(2 slots) x cg(32 groups of 8 ch); head = cg>>3.

__global__ __launch_bounds__(256, 4) void k_agg(
    const ushort* __restrict__ hb, const ushort* __restrict__ xs,
    const float* __restrict__ a4T, const float* __restrict__ acls,
    const float* __restrict__ aself, const float* __restrict__ aclsinT,
    const int* __restrict__ cursor, const int* __restrict__ csr,
    const int* __restrict__ batch, const int* __restrict__ lo,
    const int* __restrict__ hi,
    const float* __restrict__ b_gat, const float* __restrict__ ln_g,
    const float* __restrict__ ln_b,
    ushort* __restrict__ h_out, int n_new, int B)
{
    int t = threadIdx.x, w = t >> 6, lane = t & 63;
    int n = blockIdx.x * 4 + w;
    if (n >= n_new) return;
    int es = lane >> 5, cg = lane & 31, head = cg >> 3;
    const int NSLOT = n_new * CAP;

    float acc[8] = {0.f, 0.f, 0.f, 0.f, 0.f, 0.f, 0.f, 0.f};
    float den = 0.f;

    if (n >= B) {
        int gdeg = cursor[n];
        gdeg = gdeg < CAP ? gdeg : CAP;
        int gdegp = (gdeg + 7) & ~7;
        int clssrc = batch[n - B];
        bf16x8 xcls  = *((const bf16x8*)(xs + (size_t)clssrc * HID) + cg);
        bf16x8 xself = *((const bf16x8*)(xs + (size_t)n * HID) + cg);
        float acl = acls[n * 4 + head];
        float asf = aself[n * 4 + head];

        const int4* cp = (const int4*)(csr + n * CAP);
        const float4* ap = (const float4*)(a4T + (size_t)head * NSLOT + (size_t)n * CAP);
#pragma unroll 2
        for (int eb = 0; eb < gdegp; eb += 8) {
            int idx = (eb >> 2) + es;
            int4 s4 = cp[idx];
            float4 av = ap[idx];
            int s0 = s4.x < 0 ? 0 : s4.x;
            int s1 = s4.y < 0 ? 0 : s4.y;
            int s2 = s4.z < 0 ? 0 : s4.z;
            int s3 = s4.w < 0 ? 0 : s4.w;
            bf16x8 x0 = *((const bf16x8*)(xs + (size_t)s0 * HID) + cg);
            bf16x8 x1 = *((const bf16x8*)(xs + (size_t)s1 * HID) + cg);
            bf16x8 x2 = *((const bf16x8*)(xs + (size_t)s2 * HID) + cg);
            bf16x8 x3 = *((const bf16x8*)(xs + (size_t)s3 * HID) + cg);
            den += av.x + av.y + av.z + av.w;
#pragma unroll
            for (int j = 0; j < 8; ++j) {
                acc[j] += av.x * bf2f((unsigned short)x0[j]);
                acc[j] += av.y * bf2f((unsigned short)x1[j]);
                acc[j] += av.z * bf2f((unsigned short)x2[j]);
                acc[j] += av.w * bf2f((unsigned short)x3[j]);
            }
        }
        if (es == 0) {
            den += acl + asf;
#pragma unroll
            for (int j = 0; j < 8; ++j)
                acc[j] += acl * bf2f((unsigned short)xcls[j]) +
                          asf * bf2f((unsigned short)xself[j]);
        }
    } else {
        // CLS node: contiguous source range [B+lo, B+hi); weights planar.
        int cb = B + lo[n], cdeg = hi[n] - lo[n];
        bf16x8 xself = *((const bf16x8*)(xs + (size_t)n * HID) + cg);
        float asf = aself[n * 4 + head];
        const float* wp = aclsinT + (size_t)head * n_new;
        for (int eb = 0; eb < cdeg; eb += 8) {
            int b0 = eb + es * 4;
#pragma unroll
            for (int k = 0; k < 4; ++k) {
                int e = b0 + k;
                int ec = e < cdeg ? e : cdeg - 1;
                int src = cb + ec;
                float a = e < cdeg ? wp[src] : 0.f;
                bf16x8 xv = *((const bf16x8*)(xs + (size_t)src * HID) + cg);
                den += a;
#pragma unroll
                for (int j = 0; j < 8; ++j) acc[j] += a * bf2f((unsigned short)xv[j]);
            }
        }
        if (es == 0) {
            den += asf;
#pragma unroll
            for (int j = 0; j < 8; ++j) acc[j] += asf * bf2f((unsigned short)xself[j]);
        }
    }

    // reduce across the two edge slots (xor bit 5)
#pragma unroll
    for (int j = 0; j < 8; ++j) acc[j] += __shfl_xor(acc[j], 32, 64);
    den += __shfl_xor(den, 32, 64);
    float inv = 1.f / (den + 1e-16f);

    // residual + bias
    bf16x8 hv = *((const bf16x8*)(hb + (size_t)n * HID) + cg);
    const float4* bgp = (const float4*)(b_gat + cg * 8);
    float4 bg0 = bgp[0], bg1 = bgp[1];
    float bg[8] = {bg0.x, bg0.y, bg0.z, bg0.w, bg1.x, bg1.y, bg1.z, bg1.w};
    float r[8];
#pragma unroll
    for (int j = 0; j < 8; ++j)
        r[j] = bf2f((unsigned short)hv[j]) + acc[j] * inv + bg[j];

    // LayerNorm: butterfly over the 32 channel groups (bits 0..4)
    float ss = 0.f;
#pragma unroll
    for (int j = 0; j < 8; ++j) ss += r[j];
#pragma unroll
    for (int o = 1; o < 32; o <<= 1) ss += __shfl_xor(ss, o, 64);
    float mu = ss * (1.f / HID);
    float vv = 0.f;
#pragma unroll
    for (int j = 0; j < 8; ++j) { r[j] -= mu; vv += r[j] * r[j]; }
#pragma unroll
    for (int o = 1; o < 32; o <<= 1) vv += __shfl_xor(vv, o, 64);
    float rs = rsqrtf(vv * (1.f / HID) + EPS);

    if (es == 0) {
        const float4* gp = (const float4*)(ln_g + cg * 8);
        const float4* bp = (const float4*)(ln_b + cg * 8);
        float4 g0 = gp[0], g1 = gp[1];
        float4 lb0 = bp[0], lb1 = bp[1];
        float gg[8] = {g0.x, g0.y, g0.z, g0.w, g1.x, g1.y, g1.z, g1.w};
        float bb[8] = {lb0.x, lb0.y, lb0.z, lb0.w, lb1.x, lb1.y, lb1.z, lb1.w};
        bf16x8 o8;
#pragma unroll
        for (int j = 0; j < 8; ++j) o8[j] = (short)f2bf(r[j] * rs * gg[j] + bb[j]);
        *((bf16x8*)(h_out + (size_t)n * HID) + cg) = o8;
    }
}

// ---------------- output projection (B x 256 @ 256 x 256) ----------------

__global__ __launch_bounds__(256) void k_out(
    const ushort* __restrict__ h, const float* __restrict__ Wm,
    const float* __restrict__ bias, float* __restrict__ z)
{
    __shared__ float hs[HID];
    int b = blockIdx.x, t = threadIdx.x;
    hs[t] = bf2f(h[(size_t)b * HID + t]);
    __syncthreads();
    float acc = bias[t];
#pragma unroll 8
    for (int k = 0; k < HID; ++k) acc += hs[k] * Wm[k * HID + t];
    z[(size_t)b * HID + t] = acc;
}

// ---------------- launch ----------------

extern "C" void kernel_launch(void* const* d_in, const int* in_sizes, int n_in,
                              void* d_out, int out_size, void* d_ws, size_t ws_size,
                              hipStream_t stream) {
    const float* x      = (const float*)d_in[0];
    const int*   ei     = (const int*)d_in[1];
    const int*   batch  = (const int*)d_in[2];
    const float* W_in   = (const float*)d_in[3];
    const float* b_in   = (const float*)d_in[4];
    const float* cls    = (const float*)d_in[5];
    const float* W_gat  = (const float*)d_in[6];
    const float* att_s  = (const float*)d_in[7];
    const float* att_d  = (const float*)d_in[8];
    const float* b_gat  = (const float*)d_in[9];
    const float* ln_g   = (const float*)d_in[10];
    const float* ln_b   = (const float*)d_in[11];
    const float* W_out  = (const float*)d_in[12];
    const float* b_out  = (const float*)d_in[13];

    const int N = in_sizes[0] / 128;
    const int E = in_sizes[1] / 2;
    const int B = 64;
    const int n_new = N + B;
    const int* src0 = ei;
    const int* dst0 = ei + E;

    char* p = (char*)d_ws;
    auto alloc = [&](size_t bytes) -> void* {
        void* r = (void*)p;
        p += (bytes + 255) & ~(size_t)255;
        return r;
    };
    int*    cursor = (int*)alloc((size_t)n_new * 4);
    int*    csr    = (int*)alloc((size_t)n_new * CAP * 4);
    int*    lo     = (int*)alloc((size_t)B * 4);
    int*    hi     = (int*)alloc((size_t)B * 4);
    ushort* xb     = (ushort*)alloc((size_t)N * 128 * 2);
    ushort* h0b    = (ushort*)alloc((size_t)n_new * HID * 2);
    ushort* h1b    = (ushort*)alloc((size_t)n_new * HID * 2);
    ushort* xsb    = (ushort*)alloc((size_t)n_new * HID * 2);
    float*  als    = (float*)alloc((size_t)n_new * 4 * 4);
    float*  aldv   = (float*)alloc((size_t)n_new * 4 * 4);
    float*  a4T    = (float*)alloc((size_t)n_new * CAP * 4 * 4);
    float*  acls   = (float*)alloc((size_t)n_new * 4 * 4);
    float*  aselfv = (float*)alloc((size_t)n_new * 4 * 4);
    float*  aclsinT= (float*)alloc((size_t)n_new * 4 * 4);
    ushort* wf_in  = (ushort*)alloc((size_t)4 * 1024 * 8 * 2);
    ushort* wf_gat = (ushort*)alloc((size_t)3 * 8 * 1024 * 8 * 2);

    const int nb_pre = (N * 128 / 4 + 255) / 256 + (n_new + 255) / 256 +
                       (n_new * CAP + 255) / 256 + (N + 255) / 256 +
                       (B * HID / 4 + 255) / 256 +
                       (4 * 1024 + 255) / 256 + (3 * 8 * 1024 + 255) / 256;
    k_pre<<<nb_pre, 256, 0, stream>>>(x, xb, cls, h0b, W_in, wf_in, W_gat, wf_gat,
                                      batch, lo, hi, cursor, csr, N, B, n_new);
    k_fill<<<(E + 255) / 256, 256, 0, stream>>>(src0, dst0, cursor, csr, E, B);

    k_mgemm<4, false, true><<<(N + 63) / 64, 128, 0, stream>>>(
        xb, wf_in, b_in, h0b + (size_t)B * HID, nullptr, nullptr, nullptr, nullptr, N);

    const int nb_alpha = (n_new * CAP + n_new + 255) / 256;
    ushort* cur = h0b;
    ushort* nxt = h1b;
    for (int l = 0; l < 3; ++l) {
        k_mgemm<8, true, false><<<(n_new + 63) / 64, 128, 0, stream>>>(
            cur, wf_gat + (size_t)l * 65536, nullptr, xsb,
            att_s + l * HID, att_d + l * HID, als, aldv, n_new);
        k_alpha<<<nb_alpha, 256, 0, stream>>>(
            csr, cursor, als, aldv, batch, a4T, acls, aselfv, aclsinT, n_new, B);
        k_agg<<<(n_new + 3) / 4, 256, 0, stream>>>(
            cur, xsb, a4T, acls, aselfv, aclsinT, cursor, csr, batch, lo, hi,
            b_gat + l * HID, ln_g + l * HID, ln_b + l * HID, nxt, n_new, B);
        ushort* tmp = cur; cur = nxt; nxt = tmp;
    }
    k_out<<<B, 256, 0, stream>>>(cur, W_out, b_out, (float*)d_out);
}

// Round 10
// 213.944 us; speedup vs baseline: 1.6558x; 1.1627x over previous
//
#include <hip/hip_runtime.h>
#include <hip/hip_bf16.h>

constexpr int HID = 256;
constexpr int CAP = 64;          // fixed CSR capacity/node (mean deg 16, P(>64)~1e-19)
constexpr float NEG = 0.2f;
constexpr float EPS = 1e-5f;

typedef __attribute__((ext_vector_type(8))) short bf16x8;
typedef __attribute__((ext_vector_type(4))) float f32x4;

static __device__ __forceinline__ unsigned short f2bf(float f) {
    unsigned u = __builtin_bit_cast(unsigned, f);
    u += 0x7fffu + ((u >> 16) & 1u);
    return (unsigned short)(u >> 16);
}
static __device__ __forceinline__ float bf2f(unsigned short h) {
    return __builtin_bit_cast(float, ((unsigned)h) << 16);
}
static __device__ __forceinline__ float elk(float v) {
    v = v > 0.f ? v : NEG * v;
    return __expf(v);
}

// ---------------- fused preprocessing ----------------
// NOTE: lo/hi written ONLY by the bounds task (each graph id exactly once);
// zero-initializing them here would race (round-4 bug). csr is -1-initialized
// here; k_fill (stream-ordered later) overwrites real slots.

__device__ __forceinline__ void frag_task(const float* __restrict__ W,
                                          ushort* __restrict__ out,
                                          int KS, int nmat, int q) {
    int per = KS * 1024;
    if (q >= per * nmat) return;
    int mat = q / per, r = q - mat * per;
    int l = r & 63, nf = (r >> 6) & 15, kk = r >> 10;
    const float* Wm = W + (size_t)mat * KS * 32 * 256;
    int kb = kk * 32 + ((l >> 4) << 3);
    int col = nf * 16 + (l & 15);
    bf16x8 v;
#pragma unroll
    for (int j = 0; j < 8; ++j) v[j] = (short)f2bf(Wm[(size_t)(kb + j) * 256 + col]);
    *(bf16x8*)(out + (size_t)q * 8) = v;
}

__global__ void k_pre(const float* __restrict__ x, ushort* __restrict__ xb,
                      const float* __restrict__ cls, ushort* __restrict__ h0,
                      const float* __restrict__ W_in, ushort* __restrict__ wf_in,
                      const float* __restrict__ W_gat, ushort* __restrict__ wf_gat,
                      const int* __restrict__ batch, int* lo, int* hi,
                      int* cursor, int* csr, int N, int B, int n_new) {
    int bid = blockIdx.x, t = threadIdx.x;
    const int nb_cvt  = (N * 128 / 4 + 255) / 256;
    const int nb_init = (n_new + 255) / 256;
    const int nb_csr  = (n_new * CAP + 255) / 256;
    const int nb_bnd  = (N + 255) / 256;
    const int nb_cls  = (B * HID / 4 + 255) / 256;
    const int nb_fin  = (4 * 1024 + 255) / 256;

    if (bid < nb_cvt) {
        int i = bid * 256 + t;
        int n4 = N * 128 / 4;
        if (i < n4) {
            float4 v = ((const float4*)x)[i];
            ushort4 o;
            o.x = f2bf(v.x); o.y = f2bf(v.y); o.z = f2bf(v.z); o.w = f2bf(v.w);
            ((ushort4*)xb)[i] = o;
        }
        return;
    }
    bid -= nb_cvt;
    if (bid < nb_init) {
        int i = bid * 256 + t;
        if (i < n_new) cursor[i] = 0;
        return;
    }
    bid -= nb_init;
    if (bid < nb_csr) {
        int i = bid * 256 + t;
        if (i < n_new * CAP) csr[i] = -1;
        return;
    }
    bid -= nb_csr;
    if (bid < nb_bnd) {
        int i = bid * 256 + t;
        if (i < N) {
            int b = batch[i];
            if (i == 0 || batch[i - 1] != b) lo[b] = i;
            if (i == N - 1 || batch[i + 1] != b) hi[b] = i + 1;
        }
        return;
    }
    bid -= nb_bnd;
    if (bid < nb_cls) {
        int i = bid * 256 + t;
        if (i < B * HID / 4) {
            int ch = (i & 63) * 4;
            ushort4 o;
            o.x = f2bf(cls[ch]); o.y = f2bf(cls[ch + 1]);
            o.z = f2bf(cls[ch + 2]); o.w = f2bf(cls[ch + 3]);
            ((ushort4*)h0)[i] = o;
        }
        return;
    }
    bid -= nb_cls;
    if (bid < nb_fin) {
        frag_task(W_in, wf_in, 4, 1, bid * 256 + t);
        return;
    }
    bid -= nb_fin;
    frag_task(W_gat, wf_gat, 8, 3, bid * 256 + t);
}

// ---------------- direct CSR fill (fixed capacity, no count/scan) ----------------

__global__ void k_fill(const int* __restrict__ src0, const int* __restrict__ dst0,
                       int* cursor, int* __restrict__ csr, int E, int B) {
    int e = blockIdx.x * blockDim.x + threadIdx.x;
    if (e < E) {
        int d = dst0[e] + B;
        int p = atomicAdd(&cursor[d], 1);
        if (p < CAP) csr[d * CAP + p] = src0[e] + B;
    }
}

// ---------------- per-edge attention weights (per layer) ----------------
// Fixed-stride slots: q = d*CAP + p, so dst = q>>6 (no csrd array).
// a4T[h*(n_new*CAP) + q] : weight of slot q for head h (0 for pad slots).
// Writes gated on p < padded-degree (k_agg never reads beyond it).

__global__ void k_alpha(const int* __restrict__ csr, const int* __restrict__ cursor,
                        const float* __restrict__ als, const float* __restrict__ ald,
                        const int* __restrict__ batch,
                        float* __restrict__ a4T, float* __restrict__ acls,
                        float* __restrict__ aself, float* __restrict__ aclsinT,
                        int n_new, int B) {
    const int NSLOT = n_new * CAP;
    int i = blockIdx.x * 256 + threadIdx.x;
    if (i < NSLOT) {
        int d = i >> 6, p = i & (CAP - 1);
        int deg = cursor[d];
        deg = deg < CAP ? deg : CAP;
        int degp = (deg + 7) & ~7;
        if (p >= degp) return;
        int s = csr[i];
        float ox = 0.f, oy = 0.f, oz = 0.f, ow = 0.f;
        if (s >= 0) {
            float4 s4 = ((const float4*)als)[s];
            float4 d4 = ((const float4*)ald)[d];
            ox = elk(s4.x + d4.x);
            oy = elk(s4.y + d4.y);
            oz = elk(s4.z + d4.z);
            ow = elk(s4.w + d4.w);
        }
        a4T[i] = ox;
        a4T[(size_t)NSLOT + i] = oy;
        a4T[(size_t)2 * NSLOT + i] = oz;
        a4T[(size_t)3 * NSLOT + i] = ow;
        return;
    }
    int n = i - NSLOT;
    if (n < n_new) {
        float4 d4 = ((const float4*)ald)[n];
        float4 s4 = ((const float4*)als)[n];
        float4 o;
        o.x = elk(s4.x + d4.x);
        o.y = elk(s4.y + d4.y);
        o.z = elk(s4.z + d4.z);
        o.w = elk(s4.w + d4.w);
        ((float4*)aself)[n] = o;
        if (n >= B) {
            int c = batch[n - B];
            float4 cs = ((const float4*)als)[c];
            float4 p4;
            p4.x = elk(cs.x + d4.x);
            p4.y = elk(cs.y + d4.y);
            p4.z = elk(cs.z + d4.z);
            p4.w = elk(cs.w + d4.w);
            ((float4*)acls)[n] = p4;
            float4 cd = ((const float4*)ald)[c];
            aclsinT[n] = elk(s4.x + cd.x);
            aclsinT[(size_t)n_new + n] = elk(s4.y + cd.y);
            aclsinT[(size_t)2 * n_new + n] = elk(s4.z + cd.z);
            aclsinT[(size_t)3 * n_new + n] = elk(s4.w + cd.w);
        }
    }
}

// ---------------- MFMA GEMM: out[row][0:256] = A[row][0:K] @ W ----------------
// Block = 256 threads = 4 waves. Wave w computes 32 rows x 64 cols
// (cols w*64.. = head w, so ATT logits stay wave-local). Grid (rows+31)/32.
// Per wave per kk: 2 A loads + 4 W loads + 8 MFMA; acc = 32 VGPR.
// vs round-9: 4x waves, 1/4 VGPR -> occupancy 5% -> ~25%+.

template <int KS, bool ATT, bool BIAS>
__global__ __launch_bounds__(256, 4) void k_mgemm(
    const ushort* __restrict__ A, const ushort* __restrict__ Wf,
    const float* __restrict__ bias, ushort* __restrict__ outb,
    const float* __restrict__ att_s, const float* __restrict__ att_d,
    float* __restrict__ al_s, float* __restrict__ al_d, int rows)
{
    constexpr int K = KS * 32;
    int lane = threadIdx.x & 63, w = threadIdx.x >> 6;   // w = col-group = head
    int rbase = blockIdx.x * 32;
    int arow0 = rbase + (lane & 15);
    int kofs = (lane >> 4) << 3;

    f32x4 acc[2][4];
#pragma unroll
    for (int mf = 0; mf < 2; ++mf)
#pragma unroll
        for (int nf = 0; nf < 4; ++nf) acc[mf][nf] = (f32x4){0.f, 0.f, 0.f, 0.f};

    const ushort* a0p = A + (size_t)arow0 * K + kofs;
    const ushort* a1p = a0p + (size_t)16 * K;
    bool g0 = arow0 < rows, g1 = (arow0 + 16) < rows;

#pragma unroll
    for (int kk = 0; kk < KS; ++kk) {
        bf16x8 af0 = {0, 0, 0, 0, 0, 0, 0, 0}, af1 = {0, 0, 0, 0, 0, 0, 0, 0};
        if (g0) af0 = *(const bf16x8*)(a0p + kk * 32);
        if (g1) af1 = *(const bf16x8*)(a1p + kk * 32);
        const bf16x8* wp = ((const bf16x8*)Wf) + (size_t)(kk * 16 + 4 * w) * 64 + lane;
#pragma unroll
        for (int nf = 0; nf < 4; ++nf) {
            bf16x8 bv = wp[nf * 64];
            acc[0][nf] = __builtin_amdgcn_mfma_f32_16x16x32_bf16(af0, bv, acc[0][nf], 0, 0, 0);
            acc[1][nf] = __builtin_amdgcn_mfma_f32_16x16x32_bf16(af1, bv, acc[1][nf], 0, 0, 0);
        }
    }

    int rg = (lane >> 4) * 4;
    int c0 = lane & 15;
    int colbase = w * 64;
    float bv[4];
    if (BIAS) {
#pragma unroll
        for (int nf = 0; nf < 4; ++nf) bv[nf] = bias[colbase + nf * 16 + c0];
    }
#pragma unroll
    for (int mf = 0; mf < 2; ++mf)
#pragma unroll
        for (int r = 0; r < 4; ++r) {
            int row = rbase + mf * 16 + rg + r;
            if (row < rows) {
#pragma unroll
                for (int nf = 0; nf < 4; ++nf) {
                    float v = acc[mf][nf][r];
                    if (BIAS) v += bv[nf];
                    outb[(size_t)row * HID + colbase + nf * 16 + c0] = f2bf(v);
                }
            }
        }

    if (ATT) {
        float as[4], ad[4];
#pragma unroll
        for (int nf = 0; nf < 4; ++nf) {
            as[nf] = att_s[colbase + nf * 16 + c0];
            ad[nf] = att_d[colbase + nf * 16 + c0];
        }
#pragma unroll
        for (int mf = 0; mf < 2; ++mf)
#pragma unroll
            for (int r = 0; r < 4; ++r) {
                float ps = 0.f, pd = 0.f;
#pragma unroll
                for (int nf = 0; nf < 4; ++nf) {
                    float v = acc[mf][nf][r];
                    ps += v * as[nf];
                    pd += v * ad[nf];
                }
#pragma unroll
                for (int o = 1; o < 16; o <<= 1) {
                    ps += __shfl_xor(ps, o, 64);
                    pd += __shfl_xor(pd, o, 64);
                }
                int row = rbase + mf * 16 + rg + r;
                if (c0 == 0 && row < rows) {
                    al_s[row * 4 + w] = ps;
                    al_d[row * 4 + w] = pd;
                }
            }
    }
}

// ---------------- GAT aggregation + bias + residual + LayerNorm ----------------
// Branch-free batched gather, alpha PRECOMPUTED planar (no dependent loads in
// the hot loop — round-8 inline-alpha regression lesson). Fixed-stride CSR.
// One wave per node; lane = es(2 slots) x cg(32 groups of 8 ch); head = cg>>3.

__global__ __launch_bounds__(256, 4) void k_agg(
    const ushort* __restrict__ hb, const ushort* __restrict__ xs,
    const float* __restrict__ a4T, const float* __restrict__ acls,
    const float* __restrict__ aself, const float* __restrict__ aclsinT,
    const int* __restrict__ cursor, const int* __restrict__ csr,
    const int* __restrict__ batch, const int* __restrict__ lo,
    const int* __restrict__ hi,
    const float* __restrict__ b_gat, const float* __restrict__ ln_g,
    const float* __restrict__ ln_b,
    ushort* __restrict__ h_out, int n_new, int B)
{
    int t = threadIdx.x, w = t >> 6, lane = t & 63;
    int n = blockIdx.x * 4 + w;
    if (n >= n_new) return;
    int es = lane >> 5, cg = lane & 31, head = cg >> 3;
    const int NSLOT = n_new * CAP;

    float acc[8] = {0.f, 0.f, 0.f, 0.f, 0.f, 0.f, 0.f, 0.f};
    float den = 0.f;

    if (n >= B) {
        int gdeg = cursor[n];
        gdeg = gdeg < CAP ? gdeg : CAP;
        int gdegp = (gdeg + 7) & ~7;
        int clssrc = batch[n - B];
        bf16x8 xcls  = *((const bf16x8*)(xs + (size_t)clssrc * HID) + cg);
        bf16x8 xself = *((const bf16x8*)(xs + (size_t)n * HID) + cg);
        float acl = acls[n * 4 + head];
        float asf = aself[n * 4 + head];

        const int4* cp = (const int4*)(csr + n * CAP);
        const float4* ap = (const float4*)(a4T + (size_t)head * NSLOT + (size_t)n * CAP);
#pragma unroll 2
        for (int eb = 0; eb < gdegp; eb += 8) {
            int idx = (eb >> 2) + es;
            int4 s4 = cp[idx];
            float4 av = ap[idx];
            int s0 = s4.x < 0 ? 0 : s4.x;
            int s1 = s4.y < 0 ? 0 : s4.y;
            int s2 = s4.z < 0 ? 0 : s4.z;
            int s3 = s4.w < 0 ? 0 : s4.w;
            bf16x8 x0 = *((const bf16x8*)(xs + (size_t)s0 * HID) + cg);
            bf16x8 x1 = *((const bf16x8*)(xs + (size_t)s1 * HID) + cg);
            bf16x8 x2 = *((const bf16x8*)(xs + (size_t)s2 * HID) + cg);
            bf16x8 x3 = *((const bf16x8*)(xs + (size_t)s3 * HID) + cg);
            den += av.x + av.y + av.z + av.w;
#pragma unroll
            for (int j = 0; j < 8; ++j) {
                acc[j] += av.x * bf2f((unsigned short)x0[j]);
                acc[j] += av.y * bf2f((unsigned short)x1[j]);
                acc[j] += av.z * bf2f((unsigned short)x2[j]);
                acc[j] += av.w * bf2f((unsigned short)x3[j]);
            }
        }
        if (es == 0) {
            den += acl + asf;
#pragma unroll
            for (int j = 0; j < 8; ++j)
                acc[j] += acl * bf2f((unsigned short)xcls[j]) +
                          asf * bf2f((unsigned short)xself[j]);
        }
    } else {
        // CLS node: contiguous source range [B+lo, B+hi); weights planar.
        int cb = B + lo[n], cdeg = hi[n] - lo[n];
        bf16x8 xself = *((const bf16x8*)(xs + (size_t)n * HID) + cg);
        float asf = aself[n * 4 + head];
        const float* wp = aclsinT + (size_t)head * n_new;
        for (int eb = 0; eb < cdeg; eb += 8) {
            int b0 = eb + es * 4;
#pragma unroll
            for (int k = 0; k < 4; ++k) {
                int e = b0 + k;
                int ec = e < cdeg ? e : cdeg - 1;
                int src = cb + ec;
                float a = e < cdeg ? wp[src] : 0.f;
                bf16x8 xv = *((const bf16x8*)(xs + (size_t)src * HID) + cg);
                den += a;
#pragma unroll
                for (int j = 0; j < 8; ++j) acc[j] += a * bf2f((unsigned short)xv[j]);
            }
        }
        if (es == 0) {
            den += asf;
#pragma unroll
            for (int j = 0; j < 8; ++j) acc[j] += asf * bf2f((unsigned short)xself[j]);
        }
    }

    // reduce across the two edge slots (xor bit 5)
#pragma unroll
    for (int j = 0; j < 8; ++j) acc[j] += __shfl_xor(acc[j], 32, 64);
    den += __shfl_xor(den, 32, 64);
    float inv = 1.f / (den + 1e-16f);

    // residual + bias
    bf16x8 hv = *((const bf16x8*)(hb + (size_t)n * HID) + cg);
    const float4* bgp = (const float4*)(b_gat + cg * 8);
    float4 bg0 = bgp[0], bg1 = bgp[1];
    float bg[8] = {bg0.x, bg0.y, bg0.z, bg0.w, bg1.x, bg1.y, bg1.z, bg1.w};
    float r[8];
#pragma unroll
    for (int j = 0; j < 8; ++j)
        r[j] = bf2f((unsigned short)hv[j]) + acc[j] * inv + bg[j];

    // LayerNorm: butterfly over the 32 channel groups (bits 0..4)
    float ss = 0.f;
#pragma unroll
    for (int j = 0; j < 8; ++j) ss += r[j];
#pragma unroll
    for (int o = 1; o < 32; o <<= 1) ss += __shfl_xor(ss, o, 64);
    float mu = ss * (1.f / HID);
    float vv = 0.f;
#pragma unroll
    for (int j = 0; j < 8; ++j) { r[j] -= mu; vv += r[j] * r[j]; }
#pragma unroll
    for (int o = 1; o < 32; o <<= 1) vv += __shfl_xor(vv, o, 64);
    float rs = rsqrtf(vv * (1.f / HID) + EPS);

    if (es == 0) {
        const float4* gp = (const float4*)(ln_g + cg * 8);
        const float4* bp = (const float4*)(ln_b + cg * 8);
        float4 g0 = gp[0], g1 = gp[1];
        float4 lb0 = bp[0], lb1 = bp[1];
        float gg[8] = {g0.x, g0.y, g0.z, g0.w, g1.x, g1.y, g1.z, g1.w};
        float bb[8] = {lb0.x, lb0.y, lb0.z, lb0.w, lb1.x, lb1.y, lb1.z, lb1.w};
        bf16x8 o8;
#pragma unroll
        for (int j = 0; j < 8; ++j) o8[j] = (short)f2bf(r[j] * rs * gg[j] + bb[j]);
        *((bf16x8*)(h_out + (size_t)n * HID) + cg) = o8;
    }
}

// ---------------- output projection (B x 256 @ 256 x 256) ----------------

__global__ __launch_bounds__(256) void k_out(
    const ushort* __restrict__ h, const float* __restrict__ Wm,
    const float* __restrict__ bias, float* __restrict__ z)
{
    __shared__ float hs[HID];
    int b = blockIdx.x, t = threadIdx.x;
    hs[t] = bf2f(h[(size_t)b * HID + t]);
    __syncthreads();
    float acc = bias[t];
#pragma unroll 8
    for (int k = 0; k < HID; ++k) acc += hs[k] * Wm[k * HID + t];
    z[(size_t)b * HID + t] = acc;
}

// ---------------- launch ----------------

extern "C" void kernel_launch(void* const* d_in, const int* in_sizes, int n_in,
                              void* d_out, int out_size, void* d_ws, size_t ws_size,
                              hipStream_t stream) {
    const float* x      = (const float*)d_in[0];
    const int*   ei     = (const int*)d_in[1];
    const int*   batch  = (const int*)d_in[2];
    const float* W_in   = (const float*)d_in[3];
    const float* b_in   = (const float*)d_in[4];
    const float* cls    = (const float*)d_in[5];
    const float* W_gat  = (const float*)d_in[6];
    const float* att_s  = (const float*)d_in[7];
    const float* att_d  = (const float*)d_in[8];
    const float* b_gat  = (const float*)d_in[9];
    const float* ln_g   = (const float*)d_in[10];
    const float* ln_b   = (const float*)d_in[11];
    const float* W_out  = (const float*)d_in[12];
    const float* b_out  = (const float*)d_in[13];

    const int N = in_sizes[0] / 128;
    const int E = in_sizes[1] / 2;
    const int B = 64;
    const int n_new = N + B;
    const int* src0 = ei;
    const int* dst0 = ei + E;

    char* p = (char*)d_ws;
    auto alloc = [&](size_t bytes) -> void* {
        void* r = (void*)p;
        p += (bytes + 255) & ~(size_t)255;
        return r;
    };
    int*    cursor = (int*)alloc((size_t)n_new * 4);
    int*    csr    = (int*)alloc((size_t)n_new * CAP * 4);
    int*    lo     = (int*)alloc((size_t)B * 4);
    int*    hi     = (int*)alloc((size_t)B * 4);
    ushort* xb     = (ushort*)alloc((size_t)N * 128 * 2);
    ushort* h0b    = (ushort*)alloc((size_t)n_new * HID * 2);
    ushort* h1b    = (ushort*)alloc((size_t)n_new * HID * 2);
    ushort* xsb    = (ushort*)alloc((size_t)n_new * HID * 2);
    float*  als    = (float*)alloc((size_t)n_new * 4 * 4);
    float*  aldv   = (float*)alloc((size_t)n_new * 4 * 4);
    float*  a4T    = (float*)alloc((size_t)n_new * CAP * 4 * 4);
    float*  acls   = (float*)alloc((size_t)n_new * 4 * 4);
    float*  aselfv = (float*)alloc((size_t)n_new * 4 * 4);
    float*  aclsinT= (float*)alloc((size_t)n_new * 4 * 4);
    ushort* wf_in  = (ushort*)alloc((size_t)4 * 1024 * 8 * 2);
    ushort* wf_gat = (ushort*)alloc((size_t)3 * 8 * 1024 * 8 * 2);

    const int nb_pre = (N * 128 / 4 + 255) / 256 + (n_new + 255) / 256 +
                       (n_new * CAP + 255) / 256 + (N + 255) / 256 +
                       (B * HID / 4 + 255) / 256 +
                       (4 * 1024 + 255) / 256 + (3 * 8 * 1024 + 255) / 256;
    k_pre<<<nb_pre, 256, 0, stream>>>(x, xb, cls, h0b, W_in, wf_in, W_gat, wf_gat,
                                      batch, lo, hi, cursor, csr, N, B, n_new);
    k_fill<<<(E + 255) / 256, 256, 0, stream>>>(src0, dst0, cursor, csr, E, B);

    k_mgemm<4, false, true><<<(N + 31) / 32, 256, 0, stream>>>(
        xb, wf_in, b_in, h0b + (size_t)B * HID, nullptr, nullptr, nullptr, nullptr, N);

    const int nb_alpha = (n_new * CAP + n_new + 255) / 256;
    ushort* cur = h0b;
    ushort* nxt = h1b;
    for (int l = 0; l < 3; ++l) {
        k_mgemm<8, true, false><<<(n_new + 31) / 32, 256, 0, stream>>>(
            cur, wf_gat + (size_t)l * 65536, nullptr, xsb,
            att_s + l * HID, att_d + l * HID, als, aldv, n_new);
        k_alpha<<<nb_alpha, 256, 0, stream>>>(
            csr, cursor, als, aldv, batch, a4T, acls, aselfv, aclsinT, n_new, B);
        k_agg<<<(n_new + 3) / 4, 256, 0, stream>>>(
            cur, xsb, a4T, acls, aselfv, aclsinT, cursor, csr, batch, lo, hi,
            b_gat + l * HID, ln_g + l * HID, ln_b + l * HID, nxt, n_new, B);
        ushort* tmp = cur; cur = nxt; nxt = tmp;
    }
    k_out<<<B, 256, 0, stream>>>(cur, W_out, b_out, (float*)d_out);
}

// Round 11
// 188.402 us; speedup vs baseline: 1.8802x; 1.1356x over previous
//
#include <hip/hip_runtime.h>
#include <hip/hip_bf16.h>

constexpr int HID = 256;
constexpr int CAP = 64;          // fixed CSR capacity/node (mean deg 16, P(>64)~1e-19)
constexpr float NEG = 0.2f;
constexpr float EPS = 1e-5f;

typedef __attribute__((ext_vector_type(8))) short bf16x8;
typedef __attribute__((ext_vector_type(4))) float f32x4;

static __device__ __forceinline__ unsigned short f2bf(float f) {
    unsigned u = __builtin_bit_cast(unsigned, f);
    u += 0x7fffu + ((u >> 16) & 1u);
    return (unsigned short)(u >> 16);
}
static __device__ __forceinline__ float bf2f(unsigned short h) {
    return __builtin_bit_cast(float, ((unsigned)h) << 16);
}
static __device__ __forceinline__ float elk(float v) {
    v = v > 0.f ? v : NEG * v;
    return __expf(v);
}

// ---------------- fused preprocessing ----------------
// NOTE: lo/hi written ONLY by the bounds task (each graph id exactly once);
// zero-initializing them here would race (round-4 bug). csr is -1-initialized
// here; k_fill (stream-ordered later) overwrites real slots.

__device__ __forceinline__ void frag_task(const float* __restrict__ W,
                                          ushort* __restrict__ out,
                                          int KS, int nmat, int q) {
    int per = KS * 1024;
    if (q >= per * nmat) return;
    int mat = q / per, r = q - mat * per;
    int l = r & 63, nf = (r >> 6) & 15, kk = r >> 10;
    const float* Wm = W + (size_t)mat * KS * 32 * 256;
    int kb = kk * 32 + ((l >> 4) << 3);
    int col = nf * 16 + (l & 15);
    bf16x8 v;
#pragma unroll
    for (int j = 0; j < 8; ++j) v[j] = (short)f2bf(Wm[(size_t)(kb + j) * 256 + col]);
    *(bf16x8*)(out + (size_t)q * 8) = v;
}

__global__ void k_pre(const float* __restrict__ x, ushort* __restrict__ xb,
                      const float* __restrict__ cls, ushort* __restrict__ h0,
                      const float* __restrict__ W_in, ushort* __restrict__ wf_in,
                      const float* __restrict__ W_gat, ushort* __restrict__ wf_gat,
                      const int* __restrict__ batch, int* lo, int* hi,
                      int* cursor, int* csr, int N, int B, int n_new) {
    int bid = blockIdx.x, t = threadIdx.x;
    const int nb_cvt  = (N * 128 / 4 + 255) / 256;
    const int nb_init = (n_new + 255) / 256;
    const int nb_csr  = (n_new * CAP + 255) / 256;
    const int nb_bnd  = (N + 255) / 256;
    const int nb_cls  = (B * HID / 4 + 255) / 256;
    const int nb_fin  = (4 * 1024 + 255) / 256;

    if (bid < nb_cvt) {
        int i = bid * 256 + t;
        int n4 = N * 128 / 4;
        if (i < n4) {
            float4 v = ((const float4*)x)[i];
            ushort4 o;
            o.x = f2bf(v.x); o.y = f2bf(v.y); o.z = f2bf(v.z); o.w = f2bf(v.w);
            ((ushort4*)xb)[i] = o;
        }
        return;
    }
    bid -= nb_cvt;
    if (bid < nb_init) {
        int i = bid * 256 + t;
        if (i < n_new) cursor[i] = 0;
        return;
    }
    bid -= nb_init;
    if (bid < nb_csr) {
        int i = bid * 256 + t;
        if (i < n_new * CAP) csr[i] = -1;
        return;
    }
    bid -= nb_csr;
    if (bid < nb_bnd) {
        int i = bid * 256 + t;
        if (i < N) {
            int b = batch[i];
            if (i == 0 || batch[i - 1] != b) lo[b] = i;
            if (i == N - 1 || batch[i + 1] != b) hi[b] = i + 1;
        }
        return;
    }
    bid -= nb_bnd;
    if (bid < nb_cls) {
        int i = bid * 256 + t;
        if (i < B * HID / 4) {
            int ch = (i & 63) * 4;
            ushort4 o;
            o.x = f2bf(cls[ch]); o.y = f2bf(cls[ch + 1]);
            o.z = f2bf(cls[ch + 2]); o.w = f2bf(cls[ch + 3]);
            ((ushort4*)h0)[i] = o;
        }
        return;
    }
    bid -= nb_cls;
    if (bid < nb_fin) {
        frag_task(W_in, wf_in, 4, 1, bid * 256 + t);
        return;
    }
    bid -= nb_fin;
    frag_task(W_gat, wf_gat, 8, 3, bid * 256 + t);
}

// ---------------- direct CSR fill (fixed capacity, no count/scan) ----------------

__global__ void k_fill(const int* __restrict__ src0, const int* __restrict__ dst0,
                       int* cursor, int* __restrict__ csr, int E, int B) {
    int e = blockIdx.x * blockDim.x + threadIdx.x;
    if (e < E) {
        int d = dst0[e] + B;
        int p = atomicAdd(&cursor[d], 1);
        if (p < CAP) csr[d * CAP + p] = src0[e] + B;
    }
}

// ---------------- per-edge attention weights (per layer) ----------------
// SLOTS=true: also fill a4T for every CSR slot (layers 0..1).
// SLOTS=false (last layer): node section only — CLS aggregation consumes just
// aself + aclsinT, so the 20 MB a4T pass is skipped.

template <bool SLOTS>
__global__ void k_alpha(const int* __restrict__ csr, const int* __restrict__ cursor,
                        const float* __restrict__ als, const float* __restrict__ ald,
                        const int* __restrict__ batch,
                        float* __restrict__ a4T, float* __restrict__ acls,
                        float* __restrict__ aself, float* __restrict__ aclsinT,
                        int n_new, int B) {
    const int NSLOT = n_new * CAP;
    int i = blockIdx.x * 256 + threadIdx.x;
    if (SLOTS) {
        if (i < NSLOT) {
            int d = i >> 6, p = i & (CAP - 1);
            int deg = cursor[d];
            deg = deg < CAP ? deg : CAP;
            int degp = (deg + 7) & ~7;
            if (p >= degp) return;
            int s = csr[i];
            float ox = 0.f, oy = 0.f, oz = 0.f, ow = 0.f;
            if (s >= 0) {
                float4 s4 = ((const float4*)als)[s];
                float4 d4 = ((const float4*)ald)[d];
                ox = elk(s4.x + d4.x);
                oy = elk(s4.y + d4.y);
                oz = elk(s4.z + d4.z);
                ow = elk(s4.w + d4.w);
            }
            a4T[i] = ox;
            a4T[(size_t)NSLOT + i] = oy;
            a4T[(size_t)2 * NSLOT + i] = oz;
            a4T[(size_t)3 * NSLOT + i] = ow;
            return;
        }
        i -= NSLOT;
    }
    int n = i;
    if (n < n_new) {
        float4 d4 = ((const float4*)ald)[n];
        float4 s4 = ((const float4*)als)[n];
        float4 o;
        o.x = elk(s4.x + d4.x);
        o.y = elk(s4.y + d4.y);
        o.z = elk(s4.z + d4.z);
        o.w = elk(s4.w + d4.w);
        ((float4*)aself)[n] = o;
        if (n >= B) {
            int c = batch[n - B];
            float4 cs = ((const float4*)als)[c];
            float4 p4;
            p4.x = elk(cs.x + d4.x);
            p4.y = elk(cs.y + d4.y);
            p4.z = elk(cs.z + d4.z);
            p4.w = elk(cs.w + d4.w);
            ((float4*)acls)[n] = p4;
            float4 cd = ((const float4*)ald)[c];
            aclsinT[n] = elk(s4.x + cd.x);
            aclsinT[(size_t)n_new + n] = elk(s4.y + cd.y);
            aclsinT[(size_t)2 * n_new + n] = elk(s4.z + cd.z);
            aclsinT[(size_t)3 * n_new + n] = elk(s4.w + cd.w);
        }
    }
}

// ---------------- MFMA GEMM: out[row][0:256] = A[row][0:K] @ W ----------------
// Block = 256 threads = 4 waves. Wave w computes 32 rows x 64 cols
// (cols w*64.. = head w, so ATT logits stay wave-local). Grid (rows+31)/32.

template <int KS, bool ATT, bool BIAS>
__global__ __launch_bounds__(256, 4) void k_mgemm(
    const ushort* __restrict__ A, const ushort* __restrict__ Wf,
    const float* __restrict__ bias, ushort* __restrict__ outb,
    const float* __restrict__ att_s, const float* __restrict__ att_d,
    float* __restrict__ al_s, float* __restrict__ al_d, int rows)
{
    constexpr int K = KS * 32;
    int lane = threadIdx.x & 63, w = threadIdx.x >> 6;   // w = col-group = head
    int rbase = blockIdx.x * 32;
    int arow0 = rbase + (lane & 15);
    int kofs = (lane >> 4) << 3;

    f32x4 acc[2][4];
#pragma unroll
    for (int mf = 0; mf < 2; ++mf)
#pragma unroll
        for (int nf = 0; nf < 4; ++nf) acc[mf][nf] = (f32x4){0.f, 0.f, 0.f, 0.f};

    const ushort* a0p = A + (size_t)arow0 * K + kofs;
    const ushort* a1p = a0p + (size_t)16 * K;
    bool g0 = arow0 < rows, g1 = (arow0 + 16) < rows;

#pragma unroll
    for (int kk = 0; kk < KS; ++kk) {
        bf16x8 af0 = {0, 0, 0, 0, 0, 0, 0, 0}, af1 = {0, 0, 0, 0, 0, 0, 0, 0};
        if (g0) af0 = *(const bf16x8*)(a0p + kk * 32);
        if (g1) af1 = *(const bf16x8*)(a1p + kk * 32);
        const bf16x8* wp = ((const bf16x8*)Wf) + (size_t)(kk * 16 + 4 * w) * 64 + lane;
#pragma unroll
        for (int nf = 0; nf < 4; ++nf) {
            bf16x8 bv = wp[nf * 64];
            acc[0][nf] = __builtin_amdgcn_mfma_f32_16x16x32_bf16(af0, bv, acc[0][nf], 0, 0, 0);
            acc[1][nf] = __builtin_amdgcn_mfma_f32_16x16x32_bf16(af1, bv, acc[1][nf], 0, 0, 0);
        }
    }

    int rg = (lane >> 4) * 4;
    int c0 = lane & 15;
    int colbase = w * 64;
    float bv[4];
    if (BIAS) {
#pragma unroll
        for (int nf = 0; nf < 4; ++nf) bv[nf] = bias[colbase + nf * 16 + c0];
    }
#pragma unroll
    for (int mf = 0; mf < 2; ++mf)
#pragma unroll
        for (int r = 0; r < 4; ++r) {
            int row = rbase + mf * 16 + rg + r;
            if (row < rows) {
#pragma unroll
                for (int nf = 0; nf < 4; ++nf) {
                    float v = acc[mf][nf][r];
                    if (BIAS) v += bv[nf];
                    outb[(size_t)row * HID + colbase + nf * 16 + c0] = f2bf(v);
                }
            }
        }

    if (ATT) {
        float as[4], ad[4];
#pragma unroll
        for (int nf = 0; nf < 4; ++nf) {
            as[nf] = att_s[colbase + nf * 16 + c0];
            ad[nf] = att_d[colbase + nf * 16 + c0];
        }
#pragma unroll
        for (int mf = 0; mf < 2; ++mf)
#pragma unroll
            for (int r = 0; r < 4; ++r) {
                float ps = 0.f, pd = 0.f;
#pragma unroll
                for (int nf = 0; nf < 4; ++nf) {
                    float v = acc[mf][nf][r];
                    ps += v * as[nf];
                    pd += v * ad[nf];
                }
#pragma unroll
                for (int o = 1; o < 16; o <<= 1) {
                    ps += __shfl_xor(ps, o, 64);
                    pd += __shfl_xor(pd, o, 64);
                }
                int row = rbase + mf * 16 + rg + r;
                if (c0 == 0 && row < rows) {
                    al_s[row * 4 + w] = ps;
                    al_d[row * 4 + w] = pd;
                }
            }
    }
}

// ---------------- GAT aggregation + bias + residual + LayerNorm ----------------
// Branch-free batched gather, alpha PRECOMPUTED planar (no dependent loads in
// the hot loop — round-8 inline-alpha regression lesson). Fixed-stride CSR.
// One wave per node; lane = es(2 slots) x cg(32 groups of 8 ch); head = cg>>3.

__global__ __launch_bounds__(256, 4) void k_agg(
    const ushort* __restrict__ hb, const ushort* __restrict__ xs,
    const float* __restrict__ a4T, const float* __restrict__ acls,
    const float* __restrict__ aself, const float* __restrict__ aclsinT,
    const int* __restrict__ cursor, const int* __restrict__ csr,
    const int* __restrict__ batch, const int* __restrict__ lo,
    const int* __restrict__ hi,
    const float* __restrict__ b_gat, const float* __restrict__ ln_g,
    const float* __restrict__ ln_b,
    ushort* __restrict__ h_out, int n_new, int B)
{
    int t = threadIdx.x, w = t >> 6, lane = t & 63;
    int n = blockIdx.x * 4 + w;
    if (n >= n_new) return;
    int es = lane >> 5, cg = lane & 31, head = cg >> 3;
    const int NSLOT = n_new * CAP;

    float acc[8] = {0.f, 0.f, 0.f, 0.f, 0.f, 0.f, 0.f, 0.f};
    float den = 0.f;

    if (n >= B) {
        int gdeg = cursor[n];
        gdeg = gdeg < CAP ? gdeg : CAP;
        int gdegp = (gdeg + 7) & ~7;
        int clssrc = batch[n - B];
        bf16x8 xcls  = *((const bf16x8*)(xs + (size_t)clssrc * HID) + cg);
        bf16x8 xself = *((const bf16x8*)(xs + (size_t)n * HID) + cg);
        float acl = acls[n * 4 + head];
        float asf = aself[n * 4 + head];

        const int4* cp = (const int4*)(csr + n * CAP);
        const float4* ap = (const float4*)(a4T + (size_t)head * NSLOT + (size_t)n * CAP);
#pragma unroll 2
        for (int eb = 0; eb < gdegp; eb += 8) {
            int idx = (eb >> 2) + es;
            int4 s4 = cp[idx];
            float4 av = ap[idx];
            int s0 = s4.x < 0 ? 0 : s4.x;
            int s1 = s4.y < 0 ? 0 : s4.y;
            int s2 = s4.z < 0 ? 0 : s4.z;
            int s3 = s4.w < 0 ? 0 : s4.w;
            bf16x8 x0 = *((const bf16x8*)(xs + (size_t)s0 * HID) + cg);
            bf16x8 x1 = *((const bf16x8*)(xs + (size_t)s1 * HID) + cg);
            bf16x8 x2 = *((const bf16x8*)(xs + (size_t)s2 * HID) + cg);
            bf16x8 x3 = *((const bf16x8*)(xs + (size_t)s3 * HID) + cg);
            den += av.x + av.y + av.z + av.w;
#pragma unroll
            for (int j = 0; j < 8; ++j) {
                acc[j] += av.x * bf2f((unsigned short)x0[j]);
                acc[j] += av.y * bf2f((unsigned short)x1[j]);
                acc[j] += av.z * bf2f((unsigned short)x2[j]);
                acc[j] += av.w * bf2f((unsigned short)x3[j]);
            }
        }
        if (es == 0) {
            den += acl + asf;
#pragma unroll
            for (int j = 0; j < 8; ++j)
                acc[j] += acl * bf2f((unsigned short)xcls[j]) +
                          asf * bf2f((unsigned short)xself[j]);
        }
    } else {
        // CLS node: contiguous source range [B+lo, B+hi); weights planar.
        int cb = B + lo[n], cdeg = hi[n] - lo[n];
        bf16x8 xself = *((const bf16x8*)(xs + (size_t)n * HID) + cg);
        float asf = aself[n * 4 + head];
        const float* wp = aclsinT + (size_t)head * n_new;
        for (int eb = 0; eb < cdeg; eb += 8) {
            int b0 = eb + es * 4;
#pragma unroll
            for (int k = 0; k < 4; ++k) {
                int e = b0 + k;
                int ec = e < cdeg ? e : cdeg - 1;
                int src = cb + ec;
                float a = e < cdeg ? wp[src] : 0.f;
                bf16x8 xv = *((const bf16x8*)(xs + (size_t)src * HID) + cg);
                den += a;
#pragma unroll
                for (int j = 0; j < 8; ++j) acc[j] += a * bf2f((unsigned short)xv[j]);
            }
        }
        if (es == 0) {
            den += asf;
#pragma unroll
            for (int j = 0; j < 8; ++j) acc[j] += asf * bf2f((unsigned short)xself[j]);
        }
    }

    // reduce across the two edge slots (xor bit 5)
#pragma unroll
    for (int j = 0; j < 8; ++j) acc[j] += __shfl_xor(acc[j], 32, 64);
    den += __shfl_xor(den, 32, 64);
    float inv = 1.f / (den + 1e-16f);

    // residual + bias
    bf16x8 hv = *((const bf16x8*)(hb + (size_t)n * HID) + cg);
    const float4* bgp = (const float4*)(b_gat + cg * 8);
    float4 bg0 = bgp[0], bg1 = bgp[1];
    float bg[8] = {bg0.x, bg0.y, bg0.z, bg0.w, bg1.x, bg1.y, bg1.z, bg1.w};
    float r[8];
#pragma unroll
    for (int j = 0; j < 8; ++j)
        r[j] = bf2f((unsigned short)hv[j]) + acc[j] * inv + bg[j];

    // LayerNorm: butterfly over the 32 channel groups (bits 0..4)
    float ss = 0.f;
#pragma unroll
    for (int j = 0; j < 8; ++j) ss += r[j];
#pragma unroll
    for (int o = 1; o < 32; o <<= 1) ss += __shfl_xor(ss, o, 64);
    float mu = ss * (1.f / HID);
    float vv = 0.f;
#pragma unroll
    for (int j = 0; j < 8; ++j) { r[j] -= mu; vv += r[j] * r[j]; }
#pragma unroll
    for (int o = 1; o < 32; o <<= 1) vv += __shfl_xor(vv, o, 64);
    float rs = rsqrtf(vv * (1.f / HID) + EPS);

    if (es == 0) {
        const float4* gp = (const float4*)(ln_g + cg * 8);
        const float4* bp = (const float4*)(ln_b + cg * 8);
        float4 g0 = gp[0], g1 = gp[1];
        float4 lb0 = bp[0], lb1 = bp[1];
        float gg[8] = {g0.x, g0.y, g0.z, g0.w, g1.x, g1.y, g1.z, g1.w};
        float bb[8] = {lb0.x, lb0.y, lb0.z, lb0.w, lb1.x, lb1.y, lb1.z, lb1.w};
        bf16x8 o8;
#pragma unroll
        for (int j = 0; j < 8; ++j) o8[j] = (short)f2bf(r[j] * rs * gg[j] + bb[j]);
        *((bf16x8*)(h_out + (size_t)n * HID) + cg) = o8;
    }
}

// ---------------- last-layer CLS-only aggregation (block per CLS node) ----------------
// The final output is h[:B] @ W_out, so layer 3 only needs the 64 CLS rows.
// 4 waves cooperate on one CLS node's ~313 sources; partial (acc,den) combined
// via LDS; LN block-reduced. Replaces a full k_agg (~33us) with ~3us.

__global__ __launch_bounds__(256) void k_aggcls(
    const ushort* __restrict__ hb, const ushort* __restrict__ xs,
    const float* __restrict__ aself, const float* __restrict__ aclsinT,
    const int* __restrict__ lo, const int* __restrict__ hi,
    const float* __restrict__ b_gat, const float* __restrict__ ln_g,
    const float* __restrict__ ln_b,
    ushort* __restrict__ h_out, int n_new, int B)
{
    __shared__ float sacc[4][256];
    __shared__ float sden[4][4];
    __shared__ float red[8];
    int b = blockIdx.x;                       // CLS node id (< B)
    int t = threadIdx.x, w = t >> 6, lane = t & 63;
    int es = lane >> 5, cg = lane & 31, head = cg >> 3;

    int cb = B + lo[b], cdeg = hi[b] - lo[b];
    const float* wp = aclsinT + (size_t)head * n_new;

    float acc[8] = {0.f, 0.f, 0.f, 0.f, 0.f, 0.f, 0.f, 0.f};
    float den = 0.f;
    for (int eb = w * 8; eb < cdeg; eb += 32) {
        int b0 = eb + es * 4;
#pragma unroll
        for (int k = 0; k < 4; ++k) {
            int e = b0 + k;
            int ec = e < cdeg ? e : cdeg - 1;
            int src = cb + ec;
            float a = e < cdeg ? wp[src] : 0.f;
            bf16x8 xv = *((const bf16x8*)(xs + (size_t)src * HID) + cg);
            den += a;
#pragma unroll
            for (int j = 0; j < 8; ++j) acc[j] += a * bf2f((unsigned short)xv[j]);
        }
    }
#pragma unroll
    for (int j = 0; j < 8; ++j) acc[j] += __shfl_xor(acc[j], 32, 64);
    den += __shfl_xor(den, 32, 64);
    if (es == 0) {
#pragma unroll
        for (int j = 0; j < 8; ++j) sacc[w][cg * 8 + j] = acc[j];
        if ((cg & 7) == 0) sden[w][head] = den;
    }
    __syncthreads();

    // thread t = channel c
    int c = t, hh = c >> 6;
    float atot = sacc[0][c] + sacc[1][c] + sacc[2][c] + sacc[3][c];
    float dtot = sden[0][hh] + sden[1][hh] + sden[2][hh] + sden[3][hh];
    float asf = aself[b * 4 + hh];
    atot += asf * bf2f(xs[(size_t)b * HID + c]);
    dtot += asf;
    float r = bf2f(hb[(size_t)b * HID + c]) + atot / (dtot + 1e-16f) + b_gat[c];

    // LayerNorm over 256 channels
    float s1 = r;
#pragma unroll
    for (int o = 32; o > 0; o >>= 1) s1 += __shfl_xor(s1, o, 64);
    if (lane == 0) red[w] = s1;
    __syncthreads();
    float mu = (red[0] + red[1] + red[2] + red[3]) * (1.f / HID);
    float d = r - mu;
    float v2 = d * d;
#pragma unroll
    for (int o = 32; o > 0; o >>= 1) v2 += __shfl_xor(v2, o, 64);
    if (lane == 0) red[4 + w] = v2;
    __syncthreads();
    float var = (red[4] + red[5] + red[6] + red[7]) * (1.f / HID);
    float rs = rsqrtf(var + EPS);
    h_out[(size_t)b * HID + c] = f2bf(d * rs * ln_g[c] + ln_b[c]);
}

// ---------------- output projection (B x 256 @ 256 x 256) ----------------

__global__ __launch_bounds__(256) void k_out(
    const ushort* __restrict__ h, const float* __restrict__ Wm,
    const float* __restrict__ bias, float* __restrict__ z)
{
    __shared__ float hs[HID];
    int b = blockIdx.x, t = threadIdx.x;
    hs[t] = bf2f(h[(size_t)b * HID + t]);
    __syncthreads();
    float acc = bias[t];
#pragma unroll 8
    for (int k = 0; k < HID; ++k) acc += hs[k] * Wm[k * HID + t];
    z[(size_t)b * HID + t] = acc;
}

// ---------------- launch ----------------

extern "C" void kernel_launch(void* const* d_in, const int* in_sizes, int n_in,
                              void* d_out, int out_size, void* d_ws, size_t ws_size,
                              hipStream_t stream) {
    const float* x      = (const float*)d_in[0];
    const int*   ei     = (const int*)d_in[1];
    const int*   batch  = (const int*)d_in[2];
    const float* W_in   = (const float*)d_in[3];
    const float* b_in   = (const float*)d_in[4];
    const float* cls    = (const float*)d_in[5];
    const float* W_gat  = (const float*)d_in[6];
    const float* att_s  = (const float*)d_in[7];
    const float* att_d  = (const float*)d_in[8];
    const float* b_gat  = (const float*)d_in[9];
    const float* ln_g   = (const float*)d_in[10];
    const float* ln_b   = (const float*)d_in[11];
    const float* W_out  = (const float*)d_in[12];
    const float* b_out  = (const float*)d_in[13];

    const int N = in_sizes[0] / 128;
    const int E = in_sizes[1] / 2;
    const int B = 64;
    const int n_new = N + B;
    const int* src0 = ei;
    const int* dst0 = ei + E;

    char* p = (char*)d_ws;
    auto alloc = [&](size_t bytes) -> void* {
        void* r = (void*)p;
        p += (bytes + 255) & ~(size_t)255;
        return r;
    };
    int*    cursor = (int*)alloc((size_t)n_new * 4);
    int*    csr    = (int*)alloc((size_t)n_new * CAP * 4);
    int*    lo     = (int*)alloc((size_t)B * 4);
    int*    hi     = (int*)alloc((size_t)B * 4);
    ushort* xb     = (ushort*)alloc((size_t)N * 128 * 2);
    ushort* h0b    = (ushort*)alloc((size_t)n_new * HID * 2);
    ushort* h1b    = (ushort*)alloc((size_t)n_new * HID * 2);
    ushort* xsb    = (ushort*)alloc((size_t)n_new * HID * 2);
    float*  als    = (float*)alloc((size_t)n_new * 4 * 4);
    float*  aldv   = (float*)alloc((size_t)n_new * 4 * 4);
    float*  a4T    = (float*)alloc((size_t)n_new * CAP * 4 * 4);
    float*  acls   = (float*)alloc((size_t)n_new * 4 * 4);
    float*  aselfv = (float*)alloc((size_t)n_new * 4 * 4);
    float*  aclsinT= (float*)alloc((size_t)n_new * 4 * 4);
    ushort* wf_in  = (ushort*)alloc((size_t)4 * 1024 * 8 * 2);
    ushort* wf_gat = (ushort*)alloc((size_t)3 * 8 * 1024 * 8 * 2);

    const int nb_pre = (N * 128 / 4 + 255) / 256 + (n_new + 255) / 256 +
                       (n_new * CAP + 255) / 256 + (N + 255) / 256 +
                       (B * HID / 4 + 255) / 256 +
                       (4 * 1024 + 255) / 256 + (3 * 8 * 1024 + 255) / 256;
    k_pre<<<nb_pre, 256, 0, stream>>>(x, xb, cls, h0b, W_in, wf_in, W_gat, wf_gat,
                                      batch, lo, hi, cursor, csr, N, B, n_new);
    k_fill<<<(E + 255) / 256, 256, 0, stream>>>(src0, dst0, cursor, csr, E, B);

    k_mgemm<4, false, true><<<(N + 31) / 32, 256, 0, stream>>>(
        xb, wf_in, b_in, h0b + (size_t)B * HID, nullptr, nullptr, nullptr, nullptr, N);

    const int nb_alpha = (n_new * CAP + n_new + 255) / 256;
    ushort* cur = h0b;
    ushort* nxt = h1b;
    for (int l = 0; l < 3; ++l) {
        k_mgemm<8, true, false><<<(n_new + 31) / 32, 256, 0, stream>>>(
            cur, wf_gat + (size_t)l * 65536, nullptr, xsb,
            att_s + l * HID, att_d + l * HID, als, aldv, n_new);
        if (l < 2) {
            k_alpha<true><<<nb_alpha, 256, 0, stream>>>(
                csr, cursor, als, aldv, batch, a4T, acls, aselfv, aclsinT, n_new, B);
            k_agg<<<(n_new + 3) / 4, 256, 0, stream>>>(
                cur, xsb, a4T, acls, aselfv, aclsinT, cursor, csr, batch, lo, hi,
                b_gat + l * HID, ln_g + l * HID, ln_b + l * HID, nxt, n_new, B);
        } else {
            // last layer: only the B CLS rows feed the output projection
            k_alpha<false><<<(n_new + 255) / 256, 256, 0, stream>>>(
                csr, cursor, als, aldv, batch, a4T, acls, aselfv, aclsinT, n_new, B);
            k_aggcls<<<B, 256, 0, stream>>>(
                cur, xsb, aselfv, aclsinT, lo, hi,
                b_gat + l * HID, ln_g + l * HID, ln_b + l * HID, nxt, n_new, B);
        }
        ushort* tmp = cur; cur = nxt; nxt = tmp;
    }
    k_out<<<B, 256, 0, stream>>>(cur, W_out, b_out, (float*)d_out);
}